// Round 1
// baseline (200.812 us; speedup 1.0000x reference)
//
#include <hip/hip_runtime.h>

#define B_ 64
#define T_ 4096
#define DQ_ 512
#define DF_ 256
#define H_ 8
#define D_ 64
#define EPS_ 1e-7f
#define TCH 128
#define NT_ (T_ / TCH) /* 32 */
#define PSZ 132        /* per-(b,h,chunk) partial: m, l, out[64], cs[64], pad */

typedef __attribute__((ext_vector_type(8))) short short8;
typedef __attribute__((ext_vector_type(4))) float f32x4;

static __device__ __forceinline__ unsigned short f2bf(float f) {
  union { float f; unsigned int u; } x; x.f = f;
  unsigned int u = x.u;
  unsigned int r = (u + 0x7fffu + ((u >> 16) & 1u)) >> 16; // RNE
  return (unsigned short)r;
}

// fq[b,h,d] = sum_f query[b,f] * Wq[h,f,d] + bq[h,d]   (fp32)
__global__ void prep_fq(const float* __restrict__ q, const float* __restrict__ Wq,
                        const float* __restrict__ bq, float* __restrict__ fq) {
  int bh = blockIdx.x;
  int b = bh >> 3, h = bh & 7;
  int d = threadIdx.x;
  const float* qb = q + (size_t)b * DQ_;
  const float* w = Wq + (size_t)h * DQ_ * D_ + d;
  float acc = bq[h * D_ + d];
#pragma unroll 8
  for (int f = 0; f < DQ_; ++f) acc += qb[f] * w[(size_t)f * D_];
  fq[bh * D_ + d] = acc;
}

// WfT[h][d][k] = bf16(Wf[h][k][d])
__global__ void prep_wft(const float* __restrict__ Wf, unsigned short* __restrict__ WfT) {
  int hd = blockIdx.x; // h*64 + d
  int h = hd >> 6, d = hd & 63;
  int t = threadIdx.x; // 64 threads
  const float* src = Wf + (size_t)h * DF_ * D_ + d;
  unsigned short* dst = WfT + (size_t)hd * DF_;
#pragma unroll
  for (int i = 0; i < 4; ++i) {
    int k = i * 64 + t;
    dst[k] = f2bf(src[(size_t)k * D_]);
  }
}

// Main: WG per (b, t-chunk); 8 waves = 8 heads; fused proj + online softmax + PV
__global__ __launch_bounds__(512, 2) void mha_main(
    const float* __restrict__ fact, const float* __restrict__ fq_ws,
    const unsigned short* __restrict__ WfT, const float* __restrict__ bf,
    float* __restrict__ part) {
  __shared__ unsigned short lds[TCH * DF_]; // 64 KB bf16 tile, XOR-swizzled

  int bid = blockIdx.x;
  int b = bid >> 5, tc = bid & 31;
  int tid = threadIdx.x;
  int l = tid & 63, w = tid >> 6; // wave id == head
  int dl = l & 15, kg = l >> 4;

  const float* factb = fact + ((size_t)b * T_ + (size_t)tc * TCH) * DF_;

  // B fragments for this head, held in registers: [n-tile 0..3][k-step 0..7]
  short8 bfrag[4][8];
  {
    const unsigned short* wb = WfT + (size_t)w * D_ * DF_;
#pragma unroll
    for (int n = 0; n < 4; ++n)
#pragma unroll
      for (int ks = 0; ks < 8; ++ks)
        bfrag[n][ks] = *(const short8*)(wb + (n * 16 + dl) * DF_ + ks * 32 + kg * 8);
  }
  float fqr[4], bfr[4];
#pragma unroll
  for (int n = 0; n < 4; ++n) {
    fqr[n] = fq_ws[(b * 8 + w) * D_ + n * 16 + dl];
    bfr[n] = bf[w * D_ + n * 16 + dl];
  }

  // staging: thread handles rows {w, 8+w} of each 16-row group, cols l*4..l*4+3
  float4 pre0, pre1;
  pre0 = *(const float4*)(factb + (size_t)(0 * 16 + w) * DF_ + l * 4);
  pre1 = *(const float4*)(factb + (size_t)(0 * 16 + 8 + w) * DF_ + l * 4);
  {
    int r0 = w, r1 = 8 + w;
    unsigned int lo0 = f2bf(pre0.x) | ((unsigned int)f2bf(pre0.y) << 16);
    unsigned int hi0 = f2bf(pre0.z) | ((unsigned int)f2bf(pre0.w) << 16);
    unsigned int lo1 = f2bf(pre1.x) | ((unsigned int)f2bf(pre1.y) << 16);
    unsigned int hi1 = f2bf(pre1.z) | ((unsigned int)f2bf(pre1.w) << 16);
    *(uint2*)((char*)lds + ((r0 * 512 + l * 8) ^ (w << 4))) = make_uint2(lo0, hi0);
    *(uint2*)((char*)lds + ((r1 * 512 + l * 8) ^ (w << 4))) = make_uint2(lo1, hi1);
  }
  __syncthreads();

  float m_run = -INFINITY, l_run = 0.f;
  float out_p[4] = {0.f, 0.f, 0.f, 0.f};
  float cs_p[4] = {0.f, 0.f, 0.f, 0.f};

  for (int g = 0; g < 8; ++g) {
    // prefetch next 16-row group (global -> regs), overlaps with compute below
    if (g < 7) {
      pre0 = *(const float4*)(factb + (size_t)((g + 1) * 16 + w) * DF_ + l * 4);
      pre1 = *(const float4*)(factb + (size_t)((g + 1) * 16 + 8 + w) * DF_ + l * 4);
    }

    // ---- compute m-tile g: ff[16 x 64] via MFMA ----
    f32x4 acc[4];
#pragma unroll
    for (int n = 0; n < 4; ++n) { f32x4 z = {0.f, 0.f, 0.f, 0.f}; acc[n] = z; }
    int ar = g * 16 + dl;
    int aswz = (dl & 7) << 4;
#pragma unroll
    for (int ks = 0; ks < 8; ++ks) {
      short8 a = *(const short8*)((const char*)lds + ((ar * 512 + ks * 64 + kg * 16) ^ aswz));
#pragma unroll
      for (int n = 0; n < 4; ++n)
        acc[n] = __builtin_amdgcn_mfma_f32_16x16x32_bf16(a, bfrag[n][ks], acc[n], 0, 0, 0);
    }

    float ffv[4][4];
#pragma unroll
    for (int n = 0; n < 4; ++n)
#pragma unroll
      for (int r = 0; r < 4; ++r) ffv[n][r] = acc[n][r] + bfr[n];

    // dot[t] = ff[t,:] . fq  (reduce over d: 4 in-lane n's + 16 lanes)
    float p[4];
#pragma unroll
    for (int r = 0; r < 4; ++r)
      p[r] = ffv[0][r] * fqr[0] + ffv[1][r] * fqr[1] + ffv[2][r] * fqr[2] + ffv[3][r] * fqr[3];
#pragma unroll
    for (int r = 0; r < 4; ++r) {
      p[r] += __shfl_xor(p[r], 1);
      p[r] += __shfl_xor(p[r], 2);
      p[r] += __shfl_xor(p[r], 4);
      p[r] += __shfl_xor(p[r], 8);
    }
    // online softmax update (wave-uniform running max)
    float mt = fmaxf(fmaxf(p[0], p[1]), fmaxf(p[2], p[3]));
    mt = fmaxf(mt, __shfl_xor(mt, 16));
    mt = fmaxf(mt, __shfl_xor(mt, 32));
    float mnew = fmaxf(m_run, mt);
    float scale = __expf(m_run - mnew);
    float wgt[4];
#pragma unroll
    for (int r = 0; r < 4; ++r) wgt[r] = __expf(p[r] - mnew);
    float s = wgt[0] + wgt[1] + wgt[2] + wgt[3];
    s += __shfl_xor(s, 16);
    s += __shfl_xor(s, 32);
    l_run = l_run * scale + s;
    m_run = mnew;
#pragma unroll
    for (int n = 0; n < 4; ++n) {
      out_p[n] = out_p[n] * scale +
                 (wgt[0] * ffv[n][0] + wgt[1] * ffv[n][1] + wgt[2] * ffv[n][2] + wgt[3] * ffv[n][3]);
      cs_p[n] += ffv[n][0] + ffv[n][1] + ffv[n][2] + ffv[n][3];
    }

    // commit next group to LDS (after compute, before barrier)
    if (g < 7) {
      int r0 = (g + 1) * 16 + w, r1 = (g + 1) * 16 + 8 + w;
      unsigned int lo0 = f2bf(pre0.x) | ((unsigned int)f2bf(pre0.y) << 16);
      unsigned int hi0 = f2bf(pre0.z) | ((unsigned int)f2bf(pre0.w) << 16);
      unsigned int lo1 = f2bf(pre1.x) | ((unsigned int)f2bf(pre1.y) << 16);
      unsigned int hi1 = f2bf(pre1.z) | ((unsigned int)f2bf(pre1.w) << 16);
      *(uint2*)((char*)lds + ((r0 * 512 + l * 8) ^ (w << 4))) = make_uint2(lo0, hi0);
      *(uint2*)((char*)lds + ((r1 * 512 + l * 8) ^ (w << 4))) = make_uint2(lo1, hi1);
    }
    __syncthreads();
  }

  // reduce partial accumulators across the 4 row-groups
#pragma unroll
  for (int n = 0; n < 4; ++n) {
    out_p[n] += __shfl_xor(out_p[n], 16);
    out_p[n] += __shfl_xor(out_p[n], 32);
    cs_p[n] += __shfl_xor(cs_p[n], 16);
    cs_p[n] += __shfl_xor(cs_p[n], 32);
  }
  float* pb = part + (size_t)((b * 8 + w) * NT_ + tc) * PSZ;
  if (l == 0) { pb[0] = m_run; pb[1] = l_run; }
  if (l < 16) {
#pragma unroll
    for (int n = 0; n < 4; ++n) {
      pb[2 + n * 16 + l] = out_p[n];
      pb[66 + n * 16 + l] = cs_p[n];
    }
  }
}

// combine chunk partials: out[b, h*64+d] = acc/L + EPS*colsum
__global__ void reduce_k(const float* __restrict__ part, float* __restrict__ out) {
  int bh = blockIdx.x;
  int d = threadIdx.x;
  const float* p = part + (size_t)bh * NT_ * PSZ;
  float M = -INFINITY;
#pragma unroll 4
  for (int i = 0; i < NT_; ++i) M = fmaxf(M, p[i * PSZ]);
  float L = 0.f, acc = 0.f, cs = 0.f;
#pragma unroll 4
  for (int i = 0; i < NT_; ++i) {
    float e = __expf(p[i * PSZ] - M);
    L += e * p[i * PSZ + 1];
    acc += e * p[i * PSZ + 2 + d];
    cs += p[i * PSZ + 66 + d];
  }
  int b = bh >> 3, h = bh & 7;
  out[(size_t)b * (H_ * D_) + h * D_ + d] = acc / L + EPS_ * cs;
}

extern "C" void kernel_launch(void* const* d_in, const int* in_sizes, int n_in,
                              void* d_out, int out_size, void* d_ws, size_t ws_size,
                              hipStream_t stream) {
  const float* query = (const float*)d_in[0];
  const float* fact  = (const float*)d_in[1];
  const float* Wq    = (const float*)d_in[2];
  const float* bq    = (const float*)d_in[3];
  const float* Wf    = (const float*)d_in[4];
  const float* bf    = (const float*)d_in[5];
  float* out = (float*)d_out;

  char* ws = (char*)d_ws;
  float* fq = (float*)ws;                                   // 32768 f32 = 128 KB
  unsigned short* WfT = (unsigned short*)(ws + 131072);     // 131072 bf16 = 256 KB
  float* part = (float*)(ws + 131072 + 262144);             // 64*8*32*132 f32 ≈ 8.65 MB

  prep_fq<<<dim3(B_ * H_), dim3(64), 0, stream>>>(query, Wq, bq, fq);
  prep_wft<<<dim3(H_ * D_), dim3(64), 0, stream>>>(Wf, WfT);
  mha_main<<<dim3(B_ * NT_), dim3(512), 0, stream>>>(fact, fq, WfT, bf, part);
  reduce_k<<<dim3(B_ * H_), dim3(64), 0, stream>>>(part, out);
}